// Round 9
// baseline (193.907 us; speedup 1.0000x reference)
//
#include <hip/hip_runtime.h>
#include <hip/hip_bf16.h>
#include <stdint.h>
#include <utility>

// ---------------------------------------------------------------------------
// E=64 H=64 PRE1=512 BNK=1024 S=256 P=16 B=4096. Attention branch dead
// (softmax over size-1 axis == 1). Decomposition (rel is rank-2):
//   Z1[s,i,j,k] = rx*MX[k] + ry*MY[k] + HH[16s+j][k];  Y1 = relu(Z1)
//   out = maxpool_j relu(bn2(Y1 @ Wp2))
// v19: STEP-GRANULARITY test. Evidence so far: v13(pin)/v14(ring)/v16
//   (deep)/v17(shape)/v18(2 indep WGs/CU) ALL converge to ~1360 cyc per
//   wave-step holding 256 cyc MFMA (MfmaUtil~42%). Leads >=2600cyc >> any
//   latency; independent barrier domains don't help; traffic mix doesn't
//   matter. Common denominator: one wait+fence per 8-MFMA burst, 64x/wave.
//   v19 halves step count: PAIR-steps = 16 MFMA (512cyc) per single
//   vmcnt+lgkm wait. Shape = v14 winner (4rt x 2ct). A pair-ring-2
//   ar[2][8] (lead 1 pair = 2 ksteps ~ 1100+cyc), B pair-ring-2 br[2][4].
//   Steady waits vmcnt(4) lgkm(8); boundary P16 vmcnt(16) (B16 + 12 epi
//   vm + B17 in flight; in-order retire), P17 steady again; tail 0/0.
//   Epilogues at TOP level between folds (v16 spill lesson); A2/C2 loaded
//   inside epilogue. Frags 96 + acc 128 + invariants ~15 <= 256.
//   Discriminator: 55-62us => per-step overhead was the residual;
//   69-74us => 2-wave structural ceiling, next round decides roofline.
//   LDS = Y1 128K + HH 16K = 144 KB, 1 WG/CU, 8 waves, no K-loop barriers.
// ---------------------------------------------------------------------------

typedef __bf16 bf16x8 __attribute__((ext_vector_type(8)));
typedef __bf16 bf16x2 __attribute__((ext_vector_type(2)));
typedef float  f32x4  __attribute__((ext_vector_type(4)));
typedef float  f32x2  __attribute__((ext_vector_type(2)));
typedef float  f32x16 __attribute__((ext_vector_type(16)));

// workspace layout (bytes)
#define BP2_OFF 0u          // packed Wp2, 32x32x16 B-frags: [kstep(32)][ct(32)][l(64)]*16B = 1 MB
#define BP1_OFF 1048576u    // packed W1b (Wp1 rows 64..127): [nt(32)][kb(2)][l]*16B = 64 KB
#define MX_OFF  1114112u    // 512 f32
#define MY_OFF  1116160u
#define CB_OFF  1118208u
#define SH_OFF  1120256u
#define A2_OFF  1122304u    // 1024 f32
#define C2_OFF  1126400u

// mm2 LDS layout (bytes)
#define Y1_LDS  0           // bf16 [128 r][512 k], row stride 1024 B, off = ((c16^(r&7))<<4)
#define HH_LDS  131072      // bf16 [16 j][512 k], row stride 1024 B
#define LDS_SZ  147456      // 144 KB

__device__ __forceinline__ unsigned short f2bf(float f) {
    union { float f; unsigned u; } c; c.f = f;
    unsigned u = c.u;
    return (unsigned short)((u + 0x7fffu + ((u >> 16) & 1u)) >> 16);
}
__device__ __forceinline__ float bfbits2f(unsigned hi) {
    union { unsigned u; float f; } c; c.u = hi; return c.f;
}
__device__ __forceinline__ unsigned pk_bf16(float a, float b) {
#if __has_builtin(__builtin_amdgcn_cvt_pk_bf16_f32)
    bf16x2 p = __builtin_amdgcn_cvt_pk_bf16_f32(a, b);
    union { bf16x2 v; unsigned u; } c; c.v = p; return c.u;
#else
    return (unsigned)f2bf(a) | ((unsigned)f2bf(b) << 16);
#endif
}
// Y1 address: row r (0..127), 16-byte chunk c16 (0..63).
__device__ __forceinline__ int y1off(int r, int c16) {
    return r * 1024 + ((c16 ^ (r & 7)) << 4);
}

// static_for: fold over integral_constants (C++17)
template<class F, int... Is>
__device__ __forceinline__ void sf_impl(F& f, std::integer_sequence<int, Is...>) {
    (f(std::integral_constant<int, Is>{}), ...);
}
template<int N, class F>
__device__ __forceinline__ void static_for(F&& f) {
    sf_impl(f, std::make_integer_sequence<int, N>{});
}

// ---------------------------------------------------------------------------
// prep_pack: blocks 0..255 pack Wp2 into 32x32x16 B-frag layout
// ([kstep][ct][l]); 256..271 pack W1b (16x16x32 layout for Phase A);
// 272..279 fold k-consts (64 k each, 4-way e-split + LDS reduce);
// 280..283 fold A2/C2. All global reads coalesced. UNCHANGED.
// 32x32x16 B-frag: lane l holds B[k=kstep*16+(l>>5)*8+j][n=ct*32+(l&31)].
// 16x16x32 B-frag: lane l holds B[k=kb*32+(l>>4)*8+j][n=nt*16+(l&15)].
// ---------------------------------------------------------------------------
__global__ __launch_bounds__(256) void prep_pack_kernel(
    const float* __restrict__ Wsp,  const float* __restrict__ bsp,
    const float* __restrict__ Wp1,  const float* __restrict__ bp1,
    const float* __restrict__ gp1,  const float* __restrict__ btp1,
    const float* __restrict__ mp1,  const float* __restrict__ vp1,
    const float* __restrict__ Wp2,  const float* __restrict__ bp2,
    const float* __restrict__ gp2,  const float* __restrict__ btp2,
    const float* __restrict__ mp2,  const float* __restrict__ vp2,
    unsigned char* __restrict__ ws)
{
    __shared__ float tile[32 * 65];
    __shared__ float part[3][4][64];
    const int blk = blockIdx.x, t = threadIdx.x;

    if (blk < 272) {
        const float* src; int ncols, kb, ng;
        if (blk < 256) { kb = blk >> 4; ng = blk & 15; src = Wp2; ncols = 1024; }
        else { int b2 = blk - 256; kb = b2 >> 3; ng = b2 & 7; src = Wp1 + 64 * 512; ncols = 512; }
        const int k0 = kb * 32, n0 = ng * 64;
        #pragma unroll
        for (int it = 0; it < 2; ++it) {
            int c = t + it * 256;
            int r = c >> 4, c4 = c & 15;
            float4 v = *(const float4*)(src + (k0 + r) * ncols + n0 + c4 * 4);
            tile[r * 65 + c4 * 4 + 0] = v.x;
            tile[r * 65 + c4 * 4 + 1] = v.y;
            tile[r * 65 + c4 * 4 + 2] = v.z;
            tile[r * 65 + c4 * 4 + 3] = v.w;
        }
        __syncthreads();
        if (blk < 256) {
            const int l = t & 63, ch = (t >> 6) & 1, kh = t >> 7;
            const int nl = ch * 32 + (l & 31);
            const int kl = kh * 16 + ((l >> 5) & 1) * 8;
            uint4 o;
            o.x = pk_bf16(tile[(kl + 0) * 65 + nl], tile[(kl + 1) * 65 + nl]);
            o.y = pk_bf16(tile[(kl + 2) * 65 + nl], tile[(kl + 3) * 65 + nl]);
            o.z = pk_bf16(tile[(kl + 4) * 65 + nl], tile[(kl + 5) * 65 + nl]);
            o.w = pk_bf16(tile[(kl + 6) * 65 + nl], tile[(kl + 7) * 65 + nl]);
            const int kstep = kb * 2 + kh, ct = ng * 2 + ch;
            ((uint4*)(ws + BP2_OFF))[(kstep * 32 + ct) * 64 + l] = o;
        } else {
            int ntl = t >> 6, l = t & 63;
            int nl = ntl * 16 + (l & 15), kl = (l >> 4) * 8;
            uint4 o;
            o.x = pk_bf16(tile[(kl + 0) * 65 + nl], tile[(kl + 1) * 65 + nl]);
            o.y = pk_bf16(tile[(kl + 2) * 65 + nl], tile[(kl + 3) * 65 + nl]);
            o.z = pk_bf16(tile[(kl + 4) * 65 + nl], tile[(kl + 5) * 65 + nl]);
            o.w = pk_bf16(tile[(kl + 6) * 65 + nl], tile[(kl + 7) * 65 + nl]);
            ((uint4*)(ws + BP1_OFF))[((ng * 4 + ntl) * 2 + kb) * 64 + l] = o;
        }
    } else if (blk < 280) {
        const int kk = t & 63, eq = t >> 6;
        const int k = (blk - 272) * 64 + kk;
        float mx = 0.f, my = 0.f, cb = 0.f;
        #pragma unroll
        for (int e2 = 0; e2 < 16; ++e2) {
            int e = eq * 16 + e2;
            float wv = Wp1[e * 512 + k];
            mx = fmaf(Wsp[e],      wv, mx);
            my = fmaf(Wsp[64 + e], wv, my);
            cb = fmaf(bsp[e],      wv, cb);
        }
        part[0][eq][kk] = mx; part[1][eq][kk] = my; part[2][eq][kk] = cb;
        __syncthreads();
        if (t < 64) {
            const int k2 = (blk - 272) * 64 + t;
            float mxs = part[0][0][t] + part[0][1][t] + part[0][2][t] + part[0][3][t];
            float mys = part[1][0][t] + part[1][1][t] + part[1][2][t] + part[1][3][t];
            float cbs = part[2][0][t] + part[2][1][t] + part[2][2][t] + part[2][3][t];
            float a1 = gp1[k2] * rsqrtf(vp1[k2] + 1e-5f);
            ((float*)(ws + MX_OFF))[k2] = 0.05f * a1 * mxs;
            ((float*)(ws + MY_OFF))[k2] = 0.05f * a1 * mys;
            ((float*)(ws + CB_OFF))[k2] = 0.05f * a1 * cbs + (bp1[k2] - mp1[k2]) * a1 + btp1[k2];
            ((float*)(ws + SH_OFF))[k2] = 0.05f * a1;
        }
    } else {
        int n = (blk - 280) * 256 + t;
        float a = gp2[n] * rsqrtf(vp2[n] + 1e-5f);
        ((float*)(ws + A2_OFF))[n] = a;
        ((float*)(ws + C2_OFF))[n] = btp2[n] + (bp2[n] - mp2[n]) * a;
    }
}

// ---------------------------------------------------------------------------
// Phases A+B (both barriers included). 128-row version (512 threads).
// ---------------------------------------------------------------------------
__device__ __forceinline__ void phaseAB(
    unsigned char* smem,
    const float* __restrict__ hst, const float* __restrict__ epos,
    const unsigned char* __restrict__ ws, int s, int ih, int tid)
{
    const int w    = tid >> 6;
    const int l    = tid & 63;
    const int quad = l >> 4;
    const int jl   = l & 15;

    // ---- Phase A: HH via MFMA (16x16x32) ----
    {
        union { unsigned u[4]; bf16x8 v; } afh[2];
        #pragma unroll
        for (int kb = 0; kb < 2; ++kb) {
            const float4* hp = (const float4*)(hst + (s * 16 + jl) * 64 + kb * 32 + quad * 8);
            float4 v0 = hp[0], v1 = hp[1];
            afh[kb].u[0] = pk_bf16(v0.x, v0.y);
            afh[kb].u[1] = pk_bf16(v0.z, v0.w);
            afh[kb].u[2] = pk_bf16(v1.x, v1.y);
            afh[kb].u[3] = pk_bf16(v1.z, v1.w);
        }
        const f32x4 fz = {0.f, 0.f, 0.f, 0.f};
        f32x4 acch[4] = {fz, fz, fz, fz};     // wave w -> k-cols w*64..+63
        #pragma unroll
        for (int kb = 0; kb < 2; ++kb) {
            #pragma unroll
            for (int ct = 0; ct < 4; ++ct) {
                bf16x8 bfr = *(const bf16x8*)(ws + BP1_OFF + ((((w * 4 + ct) * 2 + kb) * 64 + l) << 4));
                acch[ct] = __builtin_amdgcn_mfma_f32_16x16x32_bf16(afh[kb].v, bfr, acch[ct], 0, 0, 0);
            }
        }
        const float* SHg = (const float*)(ws + SH_OFF);
        const float* CBg = (const float*)(ws + CB_OFF);
        #pragma unroll
        for (int ct = 0; ct < 4; ++ct) {
            int col = (w * 4 + ct) * 16 + jl;        // k index
            float sh = SHg[col], cb = CBg[col];
            #pragma unroll
            for (int reg = 0; reg < 4; ++reg) {
                int j = quad * 4 + reg;
                float hv = fmaf(acch[ct][reg], sh, cb);
                *(unsigned short*)(smem + HH_LDS + j * 1024 + col * 2) = f2bf(hv);
            }
        }
    }
    __syncthreads();

    // ---- Phase B: construct Y1 (bf16, swizzled); chunk = kk*16+kc ----
    {
        const int i2 = tid >> 8;           // 0..1  (4 i each)
        const int j  = (tid >> 4) & 15;
        const int kc = tid & 15;
        float rx[4], ry[4];
        float pjx = epos[s * 32 + j * 2], pjy = epos[s * 32 + j * 2 + 1];
        #pragma unroll
        for (int ii = 0; ii < 4; ++ii) {
            int ig_ = ih * 8 + i2 * 4 + ii;
            rx[ii] = pjx - epos[s * 32 + ig_ * 2];
            ry[ii] = pjy - epos[s * 32 + ig_ * 2 + 1];
        }
        const f32x2 zero2 = {0.f, 0.f};
        #pragma unroll
        for (int kk = 0; kk < 4; ++kk) {
            int c16 = kk * 16 + kc;
            int k = c16 * 8;
            uint4 hh8 = *(const uint4*)(smem + HH_LDS + j * 1024 + k * 2);
            f32x4 mx0 = *(const f32x4*)(ws + MX_OFF + k * 4);
            f32x4 mx1 = *(const f32x4*)(ws + MX_OFF + k * 4 + 16);
            f32x4 my0 = *(const f32x4*)(ws + MY_OFF + k * 4);
            f32x4 my1 = *(const f32x4*)(ws + MY_OFF + k * 4 + 16);
            f32x2 mxp[4] = { {mx0[0],mx0[1]}, {mx0[2],mx0[3]}, {mx1[0],mx1[1]}, {mx1[2],mx1[3]} };
            f32x2 myp[4] = { {my0[0],my0[1]}, {my0[2],my0[3]}, {my1[0],my1[1]}, {my1[2],my1[3]} };
            f32x2 hhp[4];
            hhp[0][0] = bfbits2f(hh8.x << 16); hhp[0][1] = bfbits2f(hh8.x & 0xffff0000u);
            hhp[1][0] = bfbits2f(hh8.y << 16); hhp[1][1] = bfbits2f(hh8.y & 0xffff0000u);
            hhp[2][0] = bfbits2f(hh8.z << 16); hhp[2][1] = bfbits2f(hh8.z & 0xffff0000u);
            hhp[3][0] = bfbits2f(hh8.w << 16); hhp[3][1] = bfbits2f(hh8.w & 0xffff0000u);
            #pragma unroll
            for (int ii = 0; ii < 4; ++ii) {
                f32x2 rx2 = { rx[ii], rx[ii] };
                f32x2 ry2 = { ry[ii], ry[ii] };
                uint4 o;
                unsigned uu[4];
                #pragma unroll
                for (int p = 0; p < 4; ++p) {
                    f32x2 tt = __builtin_elementwise_fma(ry2, myp[p], hhp[p]);
                    tt = __builtin_elementwise_fma(rx2, mxp[p], tt);
                    tt = __builtin_elementwise_max(tt, zero2);
                    uu[p] = pk_bf16(tt[0], tt[1]);
                }
                o.x = uu[0]; o.y = uu[1]; o.z = uu[2]; o.w = uu[3];
                int r = (i2 * 4 + ii) * 16 + j;
                *(uint4*)(smem + Y1_LDS + y1off(r, c16)) = o;
            }
        }
    }
    __syncthreads();
}

// ---------------------------------------------------------------------------
// mm2 v19: WG = (scene s, i-half ih). 512 thr = 8 waves, wave = 4rt x 2ct.
// Phase C: 32 PAIR-steps (2 chunks x 16). Per pair: issue {4 B loads,
// 8 A ds_reads} for P+1, ONE wait, 16 MFMA. A/B pair-ring-2.
// ---------------------------------------------------------------------------
__global__ __launch_bounds__(512, 2) void mm2_kernel(
    const float* __restrict__ hst,
    const float* __restrict__ epos,
    const unsigned char* __restrict__ ws,
    float* __restrict__ out)
{
    __shared__ __align__(16) unsigned char smem[LDS_SZ];

    const int s   = blockIdx.x >> 1;     // 256 scenes
    const int ih  = blockIdx.x & 1;      // i-half
    const int tid = threadIdx.x;

    phaseAB(smem, hst, epos, ws, s, ih, tid);

    // ---- Phase C ----
    const int w = tid >> 6, l = tid & 63;
    const int lane31 = l & 31;           // A-frag m, C col
    const int hi = l >> 5;               // k-half; C row group
    const int sr = lane31 & 7;
    const float* A2 = (const float*)(ws + A2_OFF);
    const float* C2 = (const float*)(ws + C2_OFF);

    // A addr(rt, kn) = (av[rt] + (kn>>2)*128) ^ ((kn&3)<<5)
    int av[4];
    #pragma unroll
    for (int rt = 0; rt < 4; ++rt)
        av[rt] = Y1_LDS + (rt * 32 + lane31) * 1024 + ((hi ^ sr) << 4);

    const int ctb0 = w * 4;              // this wave's 4 coltiles
    const unsigned char* bp = ws + BP2_OFF + (ctb0 << 10) + (l << 4);
    // B addr(P, kp, c) = bp + (P>>4)*2048 + ((P&15)*2+kp)*32768 + c*1024

    const f32x16 fz16 = {0.f,0.f,0.f,0.f,0.f,0.f,0.f,0.f,
                         0.f,0.f,0.f,0.f,0.f,0.f,0.f,0.f};
    f32x16 acc[4][2];
    bf16x8 ar[2][8];       // pair-ring-2: slot = P&1; [kp*4 + rt]
    bf16x8 br[2][4];       // pair-ring-2: slot = P&1; [kp*2 + c]

    #pragma unroll
    for (int rt = 0; rt < 4; ++rt) { acc[rt][0] = fz16; acc[rt][1] = fz16; }

    // epilogue: bn2 + relu, maxpool over j, store fp32. 4 loads + 8 stores.
    // C/D 32x32: col = lane&31, row = (reg&3)+8*(reg>>2)+4*hi.
    auto epilogue = [&](int chunk) {
        #pragma unroll
        for (int c = 0; c < 2; ++c) {
            const int col = (ctb0 + chunk * 2 + c) * 32 + lane31;
            const float a2 = A2[col], c2 = C2[col];
            #pragma unroll
            for (int rt = 0; rt < 4; ++rt) {
                float mv[2];
                #pragma unroll
                for (int hg = 0; hg < 2; ++hg) {
                    float v0 = fmaxf(fmaf(acc[rt][c][hg * 8 + 0], a2, c2), 0.f);
                    float v1 = fmaxf(fmaf(acc[rt][c][hg * 8 + 1], a2, c2), 0.f);
                    float v2 = fmaxf(fmaf(acc[rt][c][hg * 8 + 2], a2, c2), 0.f);
                    float v3 = fmaxf(fmaf(acc[rt][c][hg * 8 + 3], a2, c2), 0.f);
                    float v4 = fmaxf(fmaf(acc[rt][c][hg * 8 + 4], a2, c2), 0.f);
                    float v5 = fmaxf(fmaf(acc[rt][c][hg * 8 + 5], a2, c2), 0.f);
                    float v6 = fmaxf(fmaf(acc[rt][c][hg * 8 + 6], a2, c2), 0.f);
                    float v7 = fmaxf(fmaf(acc[rt][c][hg * 8 + 7], a2, c2), 0.f);
                    float m = fmaxf(fmaxf(fmaxf(v0, v1), fmaxf(v2, v3)),
                                    fmaxf(fmaxf(v4, v5), fmaxf(v6, v7)));
                    mv[hg] = fmaxf(m, __shfl_xor(m, 32, 64));
                }
                const int iloc = rt * 2 + hi;      // hi=0 even i, hi=1 odd
                const float vout = hi ? mv[1] : mv[0];
                const int orow = s * 16 + ih * 8 + iloc;
                __builtin_nontemporal_store(vout, &out[orow * 1024 + col]);
            }
        }
    };

    // issue all loads for pair P (4 B + 8 A)
    auto issueP = [&](auto Pc) {
        constexpr int P   = decltype(Pc)::value;   // 0..31
        constexpr int sl  = P & 1;
        constexpr int ch  = P >> 4;
        constexpr int kn0 = (P & 15) * 2;          // within-chunk ksteps kn0, kn0+1
        const unsigned char* b = bp + (ch * 2048 + kn0 * 32768);
        br[sl][0] = *(const bf16x8*)(b);
        br[sl][1] = *(const bf16x8*)(b + 1024);
        br[sl][2] = *(const bf16x8*)(b + 32768);
        br[sl][3] = *(const bf16x8*)(b + 32768 + 1024);
        {
            constexpr int add = (kn0 >> 2) * 128, xr = (kn0 & 3) << 5;
            #pragma unroll
            for (int rt = 0; rt < 4; ++rt)
                ar[sl][rt] = *(const bf16x8*)(smem + ((av[rt] + add) ^ xr));
        }
        {
            constexpr int kn1 = kn0 + 1;
            constexpr int add = (kn1 >> 2) * 128, xr = (kn1 & 3) << 5;
            #pragma unroll
            for (int rt = 0; rt < 4; ++rt)
                ar[sl][4 + rt] = *(const bf16x8*)(smem + ((av[rt] + add) ^ xr));
        }
    };

    // one pair-step: issue P+1, single wait, 16-MFMA burst
    auto stepP = [&](auto Pc) {
        constexpr int P = decltype(Pc)::value;
        if constexpr (P + 1 <= 31)
            issueP(std::integral_constant<int, P + 1>{});
        // waits (in-order vmcnt retire):
        //   steady: B lead-1-pair -> vmcnt(4); A lead-1-pair -> lgkmcnt(8).
        //   P=16: B(16)@P15 + epi(4 loads + 8 stores) + B(17) in flight
        //         -> vmcnt(16); lgkm unaffected (epi shfls force full drain
        //         of older ds ops by in-order retire; compiler-counted).
        //   P=31: full drain before final epilogue.
        if constexpr (P == 16)
            asm volatile("s_waitcnt vmcnt(16) lgkmcnt(8)" ::: "memory");
        else if constexpr (P == 31)
            asm volatile("s_waitcnt vmcnt(0) lgkmcnt(0)" ::: "memory");
        else
            asm volatile("s_waitcnt vmcnt(4) lgkmcnt(8)" ::: "memory");
        __builtin_amdgcn_sched_barrier(0);
        constexpr int sl = P & 1;
        #pragma unroll
        for (int kp = 0; kp < 2; ++kp)
            #pragma unroll
            for (int c = 0; c < 2; ++c)
                #pragma unroll
                for (int rt = 0; rt < 4; ++rt)
                    acc[rt][c] = __builtin_amdgcn_mfma_f32_32x32x16_bf16(
                        ar[sl][kp * 4 + rt], br[sl][kp * 2 + c], acc[rt][c], 0, 0, 0);
    };

    // prologue: pair 0's loads
    issueP(std::integral_constant<int, 0>{});

    static_for<16>(stepP);                          // P = 0..15 (chunk 0)
    __builtin_amdgcn_sched_barrier(0);
    epilogue(0);
    #pragma unroll
    for (int rt = 0; rt < 4; ++rt) { acc[rt][0] = fz16; acc[rt][1] = fz16; }
    __builtin_amdgcn_sched_barrier(0);
    static_for<16>([&](auto kc) {                   // P = 16..31 (chunk 1)
        stepP(std::integral_constant<int, decltype(kc)::value + 16>{});
    });
    __builtin_amdgcn_sched_barrier(0);
    epilogue(1);
}

extern "C" void kernel_launch(void* const* d_in, const int* in_sizes, int n_in,
                              void* d_out, int out_size, void* d_ws, size_t ws_size,
                              hipStream_t stream) {
    const float* hst  = (const float*)d_in[0];
    const float* epos = (const float*)d_in[1];
    const float* Wsp  = (const float*)d_in[4];
    const float* bsp  = (const float*)d_in[5];
    const float* Wp1  = (const float*)d_in[20];
    const float* bp1  = (const float*)d_in[21];
    const float* gp1  = (const float*)d_in[22];
    const float* btp1 = (const float*)d_in[23];
    const float* mp1  = (const float*)d_in[24];
    const float* vp1  = (const float*)d_in[25];
    const float* Wp2  = (const float*)d_in[26];
    const float* bp2  = (const float*)d_in[27];
    const float* gp2  = (const float*)d_in[28];
    const float* btp2 = (const float*)d_in[29];
    const float* mp2  = (const float*)d_in[30];
    const float* vp2  = (const float*)d_in[31];
    unsigned char* ws = (unsigned char*)d_ws;
    float* out = (float*)d_out;

    // 256 (Wp2 pack) + 16 (W1b pack) + 8 (k-consts) + 4 (A2/C2) = 284 blocks
    prep_pack_kernel<<<284, 256, 0, stream>>>(Wsp, bsp, Wp1, bp1, gp1, btp1, mp1, vp1,
                                              Wp2, bp2, gp2, btp2, mp2, vp2, ws);
    // 256 scenes x 2 i-halves, 512 threads (8 waves)
    mm2_kernel<<<512, 512, 0, stream>>>(hst, epos, ws, out);
}

// Round 10
// 190.027 us; speedup vs baseline: 1.0204x; 1.0204x over previous
//
#include <hip/hip_runtime.h>
#include <hip/hip_bf16.h>
#include <stdint.h>
#include <utility>

// ---------------------------------------------------------------------------
// E=64 H=64 PRE1=512 BNK=1024 S=256 P=16 B=4096. Attention branch dead
// (softmax over size-1 axis == 1). Decomposition (rel is rank-2):
//   Z1[s,i,j,k] = rx*MX[k] + ry*MY[k] + HH[16s+j][k];  Y1 = relu(Z1)
//   out = maxpool_j relu(bn2(Y1 @ Wp2))
// v20: spill-free PAIR-step (the test v19 failed to run: v19's 96 frag
//   regs + 128 acc + misc > 256/wave -> spilled; FETCH31/WRITE73MB).
//   Budget law: acc 128 AGPR => frags+misc <= 128 arch => frags <= ~76.
//   v20 fits 16-MFMA-per-wait into 64 frag regs:
//   - A SINGLE-buffered (32 regs): issued at top of own pair, wait
//     lgkmcnt(0). Rationale: v13-v17 proved leads>=1 step >> latency buy
//     nothing; sibling wave's 512-cyc burst covers the A wait (2 w/SIMD).
//   - B pair-ring-2 (32 regs), lead 1 pair (~1100cyc >= L2), vmcnt(4).
//   Waits: steady vmcnt(4) lgkm(0); P=16 vmcnt(16) (B16:4 + epi:12 +
//   B17:4 in flight, in-order retire); P=31 vmcnt(0) lgkm(0).
//   Shape = v14 winner (4rt x 2ct); cached B (v17); epilogues outside
//   folds (v16); no setprio (v13==v14). Frags 64 = v14 => ~116 arch.
//   Discriminator: 55-62us => per-wait overhead confirmed; 69-74 =>
//   granularity falsified clean, structural-ceiling verdict next.
//   LDS = Y1 128K + HH 16K = 144 KB, 1 WG/CU, 8 waves, no K-loop barriers.
// ---------------------------------------------------------------------------

typedef __bf16 bf16x8 __attribute__((ext_vector_type(8)));
typedef __bf16 bf16x2 __attribute__((ext_vector_type(2)));
typedef float  f32x4  __attribute__((ext_vector_type(4)));
typedef float  f32x2  __attribute__((ext_vector_type(2)));
typedef float  f32x16 __attribute__((ext_vector_type(16)));

// workspace layout (bytes)
#define BP2_OFF 0u          // packed Wp2, 32x32x16 B-frags: [kstep(32)][ct(32)][l(64)]*16B = 1 MB
#define BP1_OFF 1048576u    // packed W1b (Wp1 rows 64..127): [nt(32)][kb(2)][l]*16B = 64 KB
#define MX_OFF  1114112u    // 512 f32
#define MY_OFF  1116160u
#define CB_OFF  1118208u
#define SH_OFF  1120256u
#define A2_OFF  1122304u    // 1024 f32
#define C2_OFF  1126400u

// mm2 LDS layout (bytes)
#define Y1_LDS  0           // bf16 [128 r][512 k], row stride 1024 B, off = ((c16^(r&7))<<4)
#define HH_LDS  131072      // bf16 [16 j][512 k], row stride 1024 B
#define LDS_SZ  147456      // 144 KB

__device__ __forceinline__ unsigned short f2bf(float f) {
    union { float f; unsigned u; } c; c.f = f;
    unsigned u = c.u;
    return (unsigned short)((u + 0x7fffu + ((u >> 16) & 1u)) >> 16);
}
__device__ __forceinline__ float bfbits2f(unsigned hi) {
    union { unsigned u; float f; } c; c.u = hi; return c.f;
}
__device__ __forceinline__ unsigned pk_bf16(float a, float b) {
#if __has_builtin(__builtin_amdgcn_cvt_pk_bf16_f32)
    bf16x2 p = __builtin_amdgcn_cvt_pk_bf16_f32(a, b);
    union { bf16x2 v; unsigned u; } c; c.v = p; return c.u;
#else
    return (unsigned)f2bf(a) | ((unsigned)f2bf(b) << 16);
#endif
}
// Y1 address: row r (0..127), 16-byte chunk c16 (0..63).
__device__ __forceinline__ int y1off(int r, int c16) {
    return r * 1024 + ((c16 ^ (r & 7)) << 4);
}

// static_for: fold over integral_constants (C++17)
template<class F, int... Is>
__device__ __forceinline__ void sf_impl(F& f, std::integer_sequence<int, Is...>) {
    (f(std::integral_constant<int, Is>{}), ...);
}
template<int N, class F>
__device__ __forceinline__ void static_for(F&& f) {
    sf_impl(f, std::make_integer_sequence<int, N>{});
}

// ---------------------------------------------------------------------------
// prep_pack: blocks 0..255 pack Wp2 into 32x32x16 B-frag layout
// ([kstep][ct][l]); 256..271 pack W1b (16x16x32 layout for Phase A);
// 272..279 fold k-consts (64 k each, 4-way e-split + LDS reduce);
// 280..283 fold A2/C2. All global reads coalesced. UNCHANGED.
// 32x32x16 B-frag: lane l holds B[k=kstep*16+(l>>5)*8+j][n=ct*32+(l&31)].
// 16x16x32 B-frag: lane l holds B[k=kb*32+(l>>4)*8+j][n=nt*16+(l&15)].
// ---------------------------------------------------------------------------
__global__ __launch_bounds__(256) void prep_pack_kernel(
    const float* __restrict__ Wsp,  const float* __restrict__ bsp,
    const float* __restrict__ Wp1,  const float* __restrict__ bp1,
    const float* __restrict__ gp1,  const float* __restrict__ btp1,
    const float* __restrict__ mp1,  const float* __restrict__ vp1,
    const float* __restrict__ Wp2,  const float* __restrict__ bp2,
    const float* __restrict__ gp2,  const float* __restrict__ btp2,
    const float* __restrict__ mp2,  const float* __restrict__ vp2,
    unsigned char* __restrict__ ws)
{
    __shared__ float tile[32 * 65];
    __shared__ float part[3][4][64];
    const int blk = blockIdx.x, t = threadIdx.x;

    if (blk < 272) {
        const float* src; int ncols, kb, ng;
        if (blk < 256) { kb = blk >> 4; ng = blk & 15; src = Wp2; ncols = 1024; }
        else { int b2 = blk - 256; kb = b2 >> 3; ng = b2 & 7; src = Wp1 + 64 * 512; ncols = 512; }
        const int k0 = kb * 32, n0 = ng * 64;
        #pragma unroll
        for (int it = 0; it < 2; ++it) {
            int c = t + it * 256;
            int r = c >> 4, c4 = c & 15;
            float4 v = *(const float4*)(src + (k0 + r) * ncols + n0 + c4 * 4);
            tile[r * 65 + c4 * 4 + 0] = v.x;
            tile[r * 65 + c4 * 4 + 1] = v.y;
            tile[r * 65 + c4 * 4 + 2] = v.z;
            tile[r * 65 + c4 * 4 + 3] = v.w;
        }
        __syncthreads();
        if (blk < 256) {
            const int l = t & 63, ch = (t >> 6) & 1, kh = t >> 7;
            const int nl = ch * 32 + (l & 31);
            const int kl = kh * 16 + ((l >> 5) & 1) * 8;
            uint4 o;
            o.x = pk_bf16(tile[(kl + 0) * 65 + nl], tile[(kl + 1) * 65 + nl]);
            o.y = pk_bf16(tile[(kl + 2) * 65 + nl], tile[(kl + 3) * 65 + nl]);
            o.z = pk_bf16(tile[(kl + 4) * 65 + nl], tile[(kl + 5) * 65 + nl]);
            o.w = pk_bf16(tile[(kl + 6) * 65 + nl], tile[(kl + 7) * 65 + nl]);
            const int kstep = kb * 2 + kh, ct = ng * 2 + ch;
            ((uint4*)(ws + BP2_OFF))[(kstep * 32 + ct) * 64 + l] = o;
        } else {
            int ntl = t >> 6, l = t & 63;
            int nl = ntl * 16 + (l & 15), kl = (l >> 4) * 8;
            uint4 o;
            o.x = pk_bf16(tile[(kl + 0) * 65 + nl], tile[(kl + 1) * 65 + nl]);
            o.y = pk_bf16(tile[(kl + 2) * 65 + nl], tile[(kl + 3) * 65 + nl]);
            o.z = pk_bf16(tile[(kl + 4) * 65 + nl], tile[(kl + 5) * 65 + nl]);
            o.w = pk_bf16(tile[(kl + 6) * 65 + nl], tile[(kl + 7) * 65 + nl]);
            ((uint4*)(ws + BP1_OFF))[((ng * 4 + ntl) * 2 + kb) * 64 + l] = o;
        }
    } else if (blk < 280) {
        const int kk = t & 63, eq = t >> 6;
        const int k = (blk - 272) * 64 + kk;
        float mx = 0.f, my = 0.f, cb = 0.f;
        #pragma unroll
        for (int e2 = 0; e2 < 16; ++e2) {
            int e = eq * 16 + e2;
            float wv = Wp1[e * 512 + k];
            mx = fmaf(Wsp[e],      wv, mx);
            my = fmaf(Wsp[64 + e], wv, my);
            cb = fmaf(bsp[e],      wv, cb);
        }
        part[0][eq][kk] = mx; part[1][eq][kk] = my; part[2][eq][kk] = cb;
        __syncthreads();
        if (t < 64) {
            const int k2 = (blk - 272) * 64 + t;
            float mxs = part[0][0][t] + part[0][1][t] + part[0][2][t] + part[0][3][t];
            float mys = part[1][0][t] + part[1][1][t] + part[1][2][t] + part[1][3][t];
            float cbs = part[2][0][t] + part[2][1][t] + part[2][2][t] + part[2][3][t];
            float a1 = gp1[k2] * rsqrtf(vp1[k2] + 1e-5f);
            ((float*)(ws + MX_OFF))[k2] = 0.05f * a1 * mxs;
            ((float*)(ws + MY_OFF))[k2] = 0.05f * a1 * mys;
            ((float*)(ws + CB_OFF))[k2] = 0.05f * a1 * cbs + (bp1[k2] - mp1[k2]) * a1 + btp1[k2];
            ((float*)(ws + SH_OFF))[k2] = 0.05f * a1;
        }
    } else {
        int n = (blk - 280) * 256 + t;
        float a = gp2[n] * rsqrtf(vp2[n] + 1e-5f);
        ((float*)(ws + A2_OFF))[n] = a;
        ((float*)(ws + C2_OFF))[n] = btp2[n] + (bp2[n] - mp2[n]) * a;
    }
}

// ---------------------------------------------------------------------------
// Phases A+B (both barriers included). 128-row version (512 threads).
// ---------------------------------------------------------------------------
__device__ __forceinline__ void phaseAB(
    unsigned char* smem,
    const float* __restrict__ hst, const float* __restrict__ epos,
    const unsigned char* __restrict__ ws, int s, int ih, int tid)
{
    const int w    = tid >> 6;
    const int l    = tid & 63;
    const int quad = l >> 4;
    const int jl   = l & 15;

    // ---- Phase A: HH via MFMA (16x16x32) ----
    {
        union { unsigned u[4]; bf16x8 v; } afh[2];
        #pragma unroll
        for (int kb = 0; kb < 2; ++kb) {
            const float4* hp = (const float4*)(hst + (s * 16 + jl) * 64 + kb * 32 + quad * 8);
            float4 v0 = hp[0], v1 = hp[1];
            afh[kb].u[0] = pk_bf16(v0.x, v0.y);
            afh[kb].u[1] = pk_bf16(v0.z, v0.w);
            afh[kb].u[2] = pk_bf16(v1.x, v1.y);
            afh[kb].u[3] = pk_bf16(v1.z, v1.w);
        }
        const f32x4 fz = {0.f, 0.f, 0.f, 0.f};
        f32x4 acch[4] = {fz, fz, fz, fz};     // wave w -> k-cols w*64..+63
        #pragma unroll
        for (int kb = 0; kb < 2; ++kb) {
            #pragma unroll
            for (int ct = 0; ct < 4; ++ct) {
                bf16x8 bfr = *(const bf16x8*)(ws + BP1_OFF + ((((w * 4 + ct) * 2 + kb) * 64 + l) << 4));
                acch[ct] = __builtin_amdgcn_mfma_f32_16x16x32_bf16(afh[kb].v, bfr, acch[ct], 0, 0, 0);
            }
        }
        const float* SHg = (const float*)(ws + SH_OFF);
        const float* CBg = (const float*)(ws + CB_OFF);
        #pragma unroll
        for (int ct = 0; ct < 4; ++ct) {
            int col = (w * 4 + ct) * 16 + jl;        // k index
            float sh = SHg[col], cb = CBg[col];
            #pragma unroll
            for (int reg = 0; reg < 4; ++reg) {
                int j = quad * 4 + reg;
                float hv = fmaf(acch[ct][reg], sh, cb);
                *(unsigned short*)(smem + HH_LDS + j * 1024 + col * 2) = f2bf(hv);
            }
        }
    }
    __syncthreads();

    // ---- Phase B: construct Y1 (bf16, swizzled); chunk = kk*16+kc ----
    {
        const int i2 = tid >> 8;           // 0..1  (4 i each)
        const int j  = (tid >> 4) & 15;
        const int kc = tid & 15;
        float rx[4], ry[4];
        float pjx = epos[s * 32 + j * 2], pjy = epos[s * 32 + j * 2 + 1];
        #pragma unroll
        for (int ii = 0; ii < 4; ++ii) {
            int ig_ = ih * 8 + i2 * 4 + ii;
            rx[ii] = pjx - epos[s * 32 + ig_ * 2];
            ry[ii] = pjy - epos[s * 32 + ig_ * 2 + 1];
        }
        const f32x2 zero2 = {0.f, 0.f};
        #pragma unroll
        for (int kk = 0; kk < 4; ++kk) {
            int c16 = kk * 16 + kc;
            int k = c16 * 8;
            uint4 hh8 = *(const uint4*)(smem + HH_LDS + j * 1024 + k * 2);
            f32x4 mx0 = *(const f32x4*)(ws + MX_OFF + k * 4);
            f32x4 mx1 = *(const f32x4*)(ws + MX_OFF + k * 4 + 16);
            f32x4 my0 = *(const f32x4*)(ws + MY_OFF + k * 4);
            f32x4 my1 = *(const f32x4*)(ws + MY_OFF + k * 4 + 16);
            f32x2 mxp[4] = { {mx0[0],mx0[1]}, {mx0[2],mx0[3]}, {mx1[0],mx1[1]}, {mx1[2],mx1[3]} };
            f32x2 myp[4] = { {my0[0],my0[1]}, {my0[2],my0[3]}, {my1[0],my1[1]}, {my1[2],my1[3]} };
            f32x2 hhp[4];
            hhp[0][0] = bfbits2f(hh8.x << 16); hhp[0][1] = bfbits2f(hh8.x & 0xffff0000u);
            hhp[1][0] = bfbits2f(hh8.y << 16); hhp[1][1] = bfbits2f(hh8.y & 0xffff0000u);
            hhp[2][0] = bfbits2f(hh8.z << 16); hhp[2][1] = bfbits2f(hh8.z & 0xffff0000u);
            hhp[3][0] = bfbits2f(hh8.w << 16); hhp[3][1] = bfbits2f(hh8.w & 0xffff0000u);
            #pragma unroll
            for (int ii = 0; ii < 4; ++ii) {
                f32x2 rx2 = { rx[ii], rx[ii] };
                f32x2 ry2 = { ry[ii], ry[ii] };
                uint4 o;
                unsigned uu[4];
                #pragma unroll
                for (int p = 0; p < 4; ++p) {
                    f32x2 tt = __builtin_elementwise_fma(ry2, myp[p], hhp[p]);
                    tt = __builtin_elementwise_fma(rx2, mxp[p], tt);
                    tt = __builtin_elementwise_max(tt, zero2);
                    uu[p] = pk_bf16(tt[0], tt[1]);
                }
                o.x = uu[0]; o.y = uu[1]; o.z = uu[2]; o.w = uu[3];
                int r = (i2 * 4 + ii) * 16 + j;
                *(uint4*)(smem + Y1_LDS + y1off(r, c16)) = o;
            }
        }
    }
    __syncthreads();
}

// ---------------------------------------------------------------------------
// mm2 v20: WG = (scene s, i-half ih). 512 thr = 8 waves, wave = 4rt x 2ct.
// Phase C: 32 PAIR-steps (2 chunks x 16). Per pair: issue 8 A ds_reads
// (own pair) + 4 B loads (pair+1), ONE wait {vmcnt(4) lgkm(0)}, 16 MFMA.
// A single-buffered (32 regs), B pair-ring-2 (32 regs) -> v14 footprint.
// ---------------------------------------------------------------------------
__global__ __launch_bounds__(512, 2) void mm2_kernel(
    const float* __restrict__ hst,
    const float* __restrict__ epos,
    const unsigned char* __restrict__ ws,
    float* __restrict__ out)
{
    __shared__ __align__(16) unsigned char smem[LDS_SZ];

    const int s   = blockIdx.x >> 1;     // 256 scenes
    const int ih  = blockIdx.x & 1;      // i-half
    const int tid = threadIdx.x;

    phaseAB(smem, hst, epos, ws, s, ih, tid);

    // ---- Phase C ----
    const int w = tid >> 6, l = tid & 63;
    const int lane31 = l & 31;           // A-frag m, C col
    const int hi = l >> 5;               // k-half; C row group
    const int sr = lane31 & 7;
    const float* A2 = (const float*)(ws + A2_OFF);
    const float* C2 = (const float*)(ws + C2_OFF);

    // A addr(rt, kn) = (av[rt] + (kn>>2)*128) ^ ((kn&3)<<5)
    int av[4];
    #pragma unroll
    for (int rt = 0; rt < 4; ++rt)
        av[rt] = Y1_LDS + (rt * 32 + lane31) * 1024 + ((hi ^ sr) << 4);

    const int ctb0 = w * 4;              // this wave's 4 coltiles
    const unsigned char* bp = ws + BP2_OFF + (ctb0 << 10) + (l << 4);
    // B addr(P, kp, c) = bp + (P>>4)*2048 + ((P&15)*2+kp)*32768 + c*1024

    const f32x16 fz16 = {0.f,0.f,0.f,0.f,0.f,0.f,0.f,0.f,
                         0.f,0.f,0.f,0.f,0.f,0.f,0.f,0.f};
    f32x16 acc[4][2];
    bf16x8 aP[8];          // A single-buffer for current pair: [kp*4 + rt]
    bf16x8 br[2][4];       // B pair-ring-2, slot = P&1: [kp*2 + c]

    #pragma unroll
    for (int rt = 0; rt < 4; ++rt) { acc[rt][0] = fz16; acc[rt][1] = fz16; }

    // epilogue: bn2 + relu, maxpool over j, store fp32. 4 loads + 8 stores.
    // C/D 32x32: col = lane&31, row = (reg&3)+8*(reg>>2)+4*hi.
    auto epilogue = [&](int chunk) {
        #pragma unroll
        for (int c = 0; c < 2; ++c) {
            const int col = (ctb0 + chunk * 2 + c) * 32 + lane31;
            const float a2 = A2[col], c2 = C2[col];
            #pragma unroll
            for (int rt = 0; rt < 4; ++rt) {
                float mv[2];
                #pragma unroll
                for (int hg = 0; hg < 2; ++hg) {
                    float v0 = fmaxf(fmaf(acc[rt][c][hg * 8 + 0], a2, c2), 0.f);
                    float v1 = fmaxf(fmaf(acc[rt][c][hg * 8 + 1], a2, c2), 0.f);
                    float v2 = fmaxf(fmaf(acc[rt][c][hg * 8 + 2], a2, c2), 0.f);
                    float v3 = fmaxf(fmaf(acc[rt][c][hg * 8 + 3], a2, c2), 0.f);
                    float v4 = fmaxf(fmaf(acc[rt][c][hg * 8 + 4], a2, c2), 0.f);
                    float v5 = fmaxf(fmaf(acc[rt][c][hg * 8 + 5], a2, c2), 0.f);
                    float v6 = fmaxf(fmaf(acc[rt][c][hg * 8 + 6], a2, c2), 0.f);
                    float v7 = fmaxf(fmaf(acc[rt][c][hg * 8 + 7], a2, c2), 0.f);
                    float m = fmaxf(fmaxf(fmaxf(v0, v1), fmaxf(v2, v3)),
                                    fmaxf(fmaxf(v4, v5), fmaxf(v6, v7)));
                    mv[hg] = fmaxf(m, __shfl_xor(m, 32, 64));
                }
                const int iloc = rt * 2 + hi;      // hi=0 even i, hi=1 odd
                const float vout = hi ? mv[1] : mv[0];
                const int orow = s * 16 + ih * 8 + iloc;
                __builtin_nontemporal_store(vout, &out[orow * 1024 + col]);
            }
        }
    };

    // issue B loads for pair PN into ring slot PN&1 (4 cached loads)
    auto issueB = [&](auto Pc) {
        constexpr int PN  = decltype(Pc)::value;   // 0..31
        constexpr int sl  = PN & 1;
        constexpr int off = (PN >> 4) * 2048 + ((PN & 15) * 2) * 32768;
        const unsigned char* b = bp + off;
        br[sl][0] = *(const bf16x8*)(b);
        br[sl][1] = *(const bf16x8*)(b + 1024);
        br[sl][2] = *(const bf16x8*)(b + 32768);
        br[sl][3] = *(const bf16x8*)(b + 32768 + 1024);
    };

    // one pair-step: issue A(P) + B(P+1), single wait, 16-MFMA burst
    auto stepP = [&](auto Pc) {
        constexpr int P = decltype(Pc)::value;
        // A for this pair (8 ds_reads, single buffer)
        {
            constexpr int kn0 = (P & 15) * 2;
            constexpr int add0 = (kn0 >> 2) * 128, xr0 = (kn0 & 3) << 5;
            #pragma unroll
            for (int rt = 0; rt < 4; ++rt)
                aP[rt] = *(const bf16x8*)(smem + ((av[rt] + add0) ^ xr0));
            constexpr int kn1 = kn0 + 1;
            constexpr int add1 = (kn1 >> 2) * 128, xr1 = (kn1 & 3) << 5;
            #pragma unroll
            for (int rt = 0; rt < 4; ++rt)
                aP[4 + rt] = *(const bf16x8*)(smem + ((av[rt] + add1) ^ xr1));
        }
        if constexpr (P + 1 <= 31)
            issueB(std::integral_constant<int, P + 1>{});
        // waits (in-order vmcnt retire):
        //   steady: B lead-1-pair -> vmcnt(4); A own-pair -> lgkmcnt(0)
        //   (sibling wave's 512-cyc burst covers the A completion).
        //   P=16: B16:4 (issued @P15) + epi(4 loads + 8 stores) + B17:4
        //         outstanding -> vmcnt(16) retires B16.
        //   P=31: no B issue; full drain.
        if constexpr (P == 16)
            asm volatile("s_waitcnt vmcnt(16) lgkmcnt(0)" ::: "memory");
        else if constexpr (P == 31)
            asm volatile("s_waitcnt vmcnt(0) lgkmcnt(0)" ::: "memory");
        else
            asm volatile("s_waitcnt vmcnt(4) lgkmcnt(0)" ::: "memory");
        __builtin_amdgcn_sched_barrier(0);
        constexpr int sl = P & 1;
        #pragma unroll
        for (int kp = 0; kp < 2; ++kp)
            #pragma unroll
            for (int c = 0; c < 2; ++c)
                #pragma unroll
                for (int rt = 0; rt < 4; ++rt)
                    acc[rt][c] = __builtin_amdgcn_mfma_f32_32x32x16_bf16(
                        aP[kp * 4 + rt], br[sl][kp * 2 + c], acc[rt][c], 0, 0, 0);
    };

    // prologue: B(0)
    issueB(std::integral_constant<int, 0>{});

    static_for<16>(stepP);                          // P = 0..15 (chunk 0)
    __builtin_amdgcn_sched_barrier(0);
    epilogue(0);
    #pragma unroll
    for (int rt = 0; rt < 4; ++rt) { acc[rt][0] = fz16; acc[rt][1] = fz16; }
    __builtin_amdgcn_sched_barrier(0);
    static_for<16>([&](auto kc) {                   // P = 16..31 (chunk 1)
        stepP(std::integral_constant<int, decltype(kc)::value + 16>{});
    });
    __builtin_amdgcn_sched_barrier(0);
    epilogue(1);
}

extern "C" void kernel_launch(void* const* d_in, const int* in_sizes, int n_in,
                              void* d_out, int out_size, void* d_ws, size_t ws_size,
                              hipStream_t stream) {
    const float* hst  = (const float*)d_in[0];
    const float* epos = (const float*)d_in[1];
    const float* Wsp  = (const float*)d_in[4];
    const float* bsp  = (const float*)d_in[5];
    const float* Wp1  = (const float*)d_in[20];
    const float* bp1  = (const float*)d_in[21];
    const float* gp1  = (const float*)d_in[22];
    const float* btp1 = (const float*)d_in[23];
    const float* mp1  = (const float*)d_in[24];
    const float* vp1  = (const float*)d_in[25];
    const float* Wp2  = (const float*)d_in[26];
    const float* bp2  = (const float*)d_in[27];
    const float* gp2  = (const float*)d_in[28];
    const float* btp2 = (const float*)d_in[29];
    const float* mp2  = (const float*)d_in[30];
    const float* vp2  = (const float*)d_in[31];
    unsigned char* ws = (unsigned char*)d_ws;
    float* out = (float*)d_out;

    // 256 (Wp2 pack) + 16 (W1b pack) + 8 (k-consts) + 4 (A2/C2) = 284 blocks
    prep_pack_kernel<<<284, 256, 0, stream>>>(Wsp, bsp, Wp1, bp1, gp1, btp1, mp1, vp1,
                                              Wp2, bp2, gp2, btp2, mp2, vp2, ws);
    // 256 scenes x 2 i-halves, 512 threads (8 waves)
    mm2_kernel<<<512, 512, 0, stream>>>(hst, epos, ws, out);
}

// Round 11
// 188.424 us; speedup vs baseline: 1.0291x; 1.0085x over previous
//
#include <hip/hip_runtime.h>
#include <hip/hip_bf16.h>
#include <stdint.h>

// ---------------------------------------------------------------------------
// E=64 H=64 PRE1=512 BNK=1024 S=256 P=16 B=4096. Attention branch dead
// (softmax over size-1 axis == 1). Decomposition (rel is rank-2):
//   Z1[s,i,j,k] = rx*MX[k] + ry*MY[k] + HH[16s+j][k];  Y1 = relu(Z1)
//   out = maxpool_j relu(bn2(Y1 @ Wp2))
// v21: v14 (proven 71.0us, no spill, VGPR 116) + PHASE STRUCTURE: the one
//   axis never tested. All barrier-free variants (v13/14/17/18/20) pin at
//   42-44% MfmaUtil; the only plain-HIP structure measured at 62% MfmaUtil
//   on this silicon at the SAME 2 waves/SIMD is the m201 8-phase template,
//   whose distinguishing features are per-phase s_barrier + setprio(1)
//   around the MFMA cluster (T5: null free-running [m190=our v13], +21-39%
//   with phases [m218b] -- barrier bounds stagger, setprio arbitrates
//   MFMA-entering vs load-issuing waves). Phase C's Y1 LDS is READ-ONLY:
//   barriers are correctness-free; uniform control flow = no deadlock.
//   Edit = redefine mfma8 as {s_barrier; setprio(1); 8 MFMA; setprio(0)}.
//   Zero register delta; counted waits/ring/epilogues = v14 verbatim.
//   v20 autopsy: single-buffered A = WAR hazard -> compiler copies ->
//   spill; pair-granularity extrapolates null anyway (92.6->77.5->~72).
//   LDS = Y1 128K + HH 16K = 144 KB, 1 WG/CU, 8 waves.
// ---------------------------------------------------------------------------

typedef __bf16 bf16x8 __attribute__((ext_vector_type(8)));
typedef __bf16 bf16x2 __attribute__((ext_vector_type(2)));
typedef float  f32x4  __attribute__((ext_vector_type(4)));
typedef float  f32x2  __attribute__((ext_vector_type(2)));
typedef float  f32x16 __attribute__((ext_vector_type(16)));

// workspace layout (bytes)
#define BP2_OFF 0u          // packed Wp2, 32x32x16 B-frags: [kstep(32)][ct(32)][l(64)]*16B = 1 MB
#define BP1_OFF 1048576u    // packed W1b (Wp1 rows 64..127): [nt(32)][kb(2)][l]*16B = 64 KB
#define MX_OFF  1114112u    // 512 f32
#define MY_OFF  1116160u
#define CB_OFF  1118208u
#define SH_OFF  1120256u
#define A2_OFF  1122304u    // 1024 f32
#define C2_OFF  1126400u

// mm2 LDS layout (bytes)
#define Y1_LDS  0           // bf16 [128 r][512 k], row stride 1024 B, off = ((c16^(r&7))<<4)
#define HH_LDS  131072      // bf16 [16 j][512 k], row stride 1024 B
#define LDS_SZ  147456      // 144 KB

#define WAITCNT(S) do { asm volatile("s_waitcnt " S ::: "memory"); \
                        __builtin_amdgcn_sched_barrier(0); } while (0)

__device__ __forceinline__ unsigned short f2bf(float f) {
    union { float f; unsigned u; } c; c.f = f;
    unsigned u = c.u;
    return (unsigned short)((u + 0x7fffu + ((u >> 16) & 1u)) >> 16);
}
__device__ __forceinline__ float bfbits2f(unsigned hi) {
    union { unsigned u; float f; } c; c.u = hi; return c.f;
}
__device__ __forceinline__ unsigned pk_bf16(float a, float b) {
#if __has_builtin(__builtin_amdgcn_cvt_pk_bf16_f32)
    bf16x2 p = __builtin_amdgcn_cvt_pk_bf16_f32(a, b);
    union { bf16x2 v; unsigned u; } c; c.v = p; return c.u;
#else
    return (unsigned)f2bf(a) | ((unsigned)f2bf(b) << 16);
#endif
}
// Y1 address: row r (0..127), 16-byte chunk c16 (0..63).
__device__ __forceinline__ int y1off(int r, int c16) {
    return r * 1024 + ((c16 ^ (r & 7)) << 4);
}

// ---------------------------------------------------------------------------
// prep_pack: blocks 0..255 pack Wp2 into 32x32x16 B-frag layout
// ([kstep][ct][l]); 256..271 pack W1b (16x16x32 layout for Phase A);
// 272..279 fold k-consts (64 k each, 4-way e-split + LDS reduce);
// 280..283 fold A2/C2. All global reads coalesced. UNCHANGED from v14.
// 32x32x16 B-frag: lane l holds B[k=kstep*16+(l>>5)*8+j][n=ct*32+(l&31)].
// 16x16x32 B-frag: lane l holds B[k=kb*32+(l>>4)*8+j][n=nt*16+(l&15)].
// ---------------------------------------------------------------------------
__global__ __launch_bounds__(256) void prep_pack_kernel(
    const float* __restrict__ Wsp,  const float* __restrict__ bsp,
    const float* __restrict__ Wp1,  const float* __restrict__ bp1,
    const float* __restrict__ gp1,  const float* __restrict__ btp1,
    const float* __restrict__ mp1,  const float* __restrict__ vp1,
    const float* __restrict__ Wp2,  const float* __restrict__ bp2,
    const float* __restrict__ gp2,  const float* __restrict__ btp2,
    const float* __restrict__ mp2,  const float* __restrict__ vp2,
    unsigned char* __restrict__ ws)
{
    __shared__ float tile[32 * 65];
    __shared__ float part[3][4][64];
    const int blk = blockIdx.x, t = threadIdx.x;

    if (blk < 272) {
        const float* src; int ncols, kb, ng;
        if (blk < 256) { kb = blk >> 4; ng = blk & 15; src = Wp2; ncols = 1024; }
        else { int b2 = blk - 256; kb = b2 >> 3; ng = b2 & 7; src = Wp1 + 64 * 512; ncols = 512; }
        const int k0 = kb * 32, n0 = ng * 64;
        #pragma unroll
        for (int it = 0; it < 2; ++it) {
            int c = t + it * 256;
            int r = c >> 4, c4 = c & 15;
            float4 v = *(const float4*)(src + (k0 + r) * ncols + n0 + c4 * 4);
            tile[r * 65 + c4 * 4 + 0] = v.x;
            tile[r * 65 + c4 * 4 + 1] = v.y;
            tile[r * 65 + c4 * 4 + 2] = v.z;
            tile[r * 65 + c4 * 4 + 3] = v.w;
        }
        __syncthreads();
        if (blk < 256) {
            const int l = t & 63, ch = (t >> 6) & 1, kh = t >> 7;
            const int nl = ch * 32 + (l & 31);
            const int kl = kh * 16 + ((l >> 5) & 1) * 8;
            uint4 o;
            o.x = pk_bf16(tile[(kl + 0) * 65 + nl], tile[(kl + 1) * 65 + nl]);
            o.y = pk_bf16(tile[(kl + 2) * 65 + nl], tile[(kl + 3) * 65 + nl]);
            o.z = pk_bf16(tile[(kl + 4) * 65 + nl], tile[(kl + 5) * 65 + nl]);
            o.w = pk_bf16(tile[(kl + 6) * 65 + nl], tile[(kl + 7) * 65 + nl]);
            const int kstep = kb * 2 + kh, ct = ng * 2 + ch;
            ((uint4*)(ws + BP2_OFF))[(kstep * 32 + ct) * 64 + l] = o;
        } else {
            int ntl = t >> 6, l = t & 63;
            int nl = ntl * 16 + (l & 15), kl = (l >> 4) * 8;
            uint4 o;
            o.x = pk_bf16(tile[(kl + 0) * 65 + nl], tile[(kl + 1) * 65 + nl]);
            o.y = pk_bf16(tile[(kl + 2) * 65 + nl], tile[(kl + 3) * 65 + nl]);
            o.z = pk_bf16(tile[(kl + 4) * 65 + nl], tile[(kl + 5) * 65 + nl]);
            o.w = pk_bf16(tile[(kl + 6) * 65 + nl], tile[(kl + 7) * 65 + nl]);
            ((uint4*)(ws + BP1_OFF))[((ng * 4 + ntl) * 2 + kb) * 64 + l] = o;
        }
    } else if (blk < 280) {
        const int kk = t & 63, eq = t >> 6;
        const int k = (blk - 272) * 64 + kk;
        float mx = 0.f, my = 0.f, cb = 0.f;
        #pragma unroll
        for (int e2 = 0; e2 < 16; ++e2) {
            int e = eq * 16 + e2;
            float wv = Wp1[e * 512 + k];
            mx = fmaf(Wsp[e],      wv, mx);
            my = fmaf(Wsp[64 + e], wv, my);
            cb = fmaf(bsp[e],      wv, cb);
        }
        part[0][eq][kk] = mx; part[1][eq][kk] = my; part[2][eq][kk] = cb;
        __syncthreads();
        if (t < 64) {
            const int k2 = (blk - 272) * 64 + t;
            float mxs = part[0][0][t] + part[0][1][t] + part[0][2][t] + part[0][3][t];
            float mys = part[1][0][t] + part[1][1][t] + part[1][2][t] + part[1][3][t];
            float cbs = part[2][0][t] + part[2][1][t] + part[2][2][t] + part[2][3][t];
            float a1 = gp1[k2] * rsqrtf(vp1[k2] + 1e-5f);
            ((float*)(ws + MX_OFF))[k2] = 0.05f * a1 * mxs;
            ((float*)(ws + MY_OFF))[k2] = 0.05f * a1 * mys;
            ((float*)(ws + CB_OFF))[k2] = 0.05f * a1 * cbs + (bp1[k2] - mp1[k2]) * a1 + btp1[k2];
            ((float*)(ws + SH_OFF))[k2] = 0.05f * a1;
        }
    } else {
        int n = (blk - 280) * 256 + t;
        float a = gp2[n] * rsqrtf(vp2[n] + 1e-5f);
        ((float*)(ws + A2_OFF))[n] = a;
        ((float*)(ws + C2_OFF))[n] = btp2[n] + (bp2[n] - mp2[n]) * a;
    }
}

// ---------------------------------------------------------------------------
// mm2 v21: WG = (scene s, i-half ih). 512 thr = 8 waves, wave = 4rt x 2ct.
// Phase A (1 barrier): HH[16x512] via 8 MFMA/wave from h x packed W1b.
// Phase B (1 barrier): construct Y1[128x512] bf16 (conflict-free mapping).
// Phase C: v14's continuous 64-step B-ring + counted waits, with per-step
//   s_barrier + setprio(1) MFMA cluster (m201/T5 phase structure).
//   Y1 is read-only in Phase C -> barriers correctness-free.
// ---------------------------------------------------------------------------
__global__ __launch_bounds__(512, 2) void mm2_kernel(
    const float* __restrict__ hst,
    const float* __restrict__ epos,
    const unsigned char* __restrict__ ws,
    float* __restrict__ out)
{
    __shared__ __align__(16) unsigned char smem[LDS_SZ];

    const int s   = blockIdx.x >> 1;     // 256 scenes
    const int ih  = blockIdx.x & 1;      // i-half
    const int tid = threadIdx.x;
    const int w    = tid >> 6;           // 0..7
    const int l    = tid & 63;
    const int quad = l >> 4;
    const int jl   = l & 15;

    // ---- Phase A: HH via MFMA (16x16x32, unchanged) ----
    {
        union { unsigned u[4]; bf16x8 v; } afh[2];
        #pragma unroll
        for (int kb = 0; kb < 2; ++kb) {
            const float4* hp = (const float4*)(hst + (s * 16 + jl) * 64 + kb * 32 + quad * 8);
            float4 v0 = hp[0], v1 = hp[1];
            afh[kb].u[0] = pk_bf16(v0.x, v0.y);
            afh[kb].u[1] = pk_bf16(v0.z, v0.w);
            afh[kb].u[2] = pk_bf16(v1.x, v1.y);
            afh[kb].u[3] = pk_bf16(v1.z, v1.w);
        }
        const f32x4 fz = {0.f, 0.f, 0.f, 0.f};
        f32x4 acch[4] = {fz, fz, fz, fz};     // wave w -> k-cols w*64..+63
        #pragma unroll
        for (int kb = 0; kb < 2; ++kb) {
            #pragma unroll
            for (int ct = 0; ct < 4; ++ct) {
                bf16x8 bfr = *(const bf16x8*)(ws + BP1_OFF + ((((w * 4 + ct) * 2 + kb) * 64 + l) << 4));
                acch[ct] = __builtin_amdgcn_mfma_f32_16x16x32_bf16(afh[kb].v, bfr, acch[ct], 0, 0, 0);
            }
        }
        const float* SHg = (const float*)(ws + SH_OFF);
        const float* CBg = (const float*)(ws + CB_OFF);
        #pragma unroll
        for (int ct = 0; ct < 4; ++ct) {
            int col = (w * 4 + ct) * 16 + jl;        // k index
            float sh = SHg[col], cb = CBg[col];
            #pragma unroll
            for (int reg = 0; reg < 4; ++reg) {
                int j = quad * 4 + reg;
                float hv = fmaf(acch[ct][reg], sh, cb);
                *(unsigned short*)(smem + HH_LDS + j * 1024 + col * 2) = f2bf(hv);
            }
        }
    }
    __syncthreads();

    // ---- Phase B: construct Y1 (bf16, swizzled); chunk = kk*16+kc ----
    {
        const int i2 = tid >> 8;           // 0..1  (4 i each)
        const int j  = (tid >> 4) & 15;
        const int kc = tid & 15;
        float rx[4], ry[4];
        float pjx = epos[s * 32 + j * 2], pjy = epos[s * 32 + j * 2 + 1];
        #pragma unroll
        for (int ii = 0; ii < 4; ++ii) {
            int ig_ = ih * 8 + i2 * 4 + ii;
            rx[ii] = pjx - epos[s * 32 + ig_ * 2];
            ry[ii] = pjy - epos[s * 32 + ig_ * 2 + 1];
        }
        const f32x2 zero2 = {0.f, 0.f};
        #pragma unroll
        for (int kk = 0; kk < 4; ++kk) {
            int c16 = kk * 16 + kc;
            int k = c16 * 8;               // = kk*128 + kc*8
            uint4 hh8 = *(const uint4*)(smem + HH_LDS + j * 1024 + k * 2);
            f32x4 mx0 = *(const f32x4*)(ws + MX_OFF + k * 4);
            f32x4 mx1 = *(const f32x4*)(ws + MX_OFF + k * 4 + 16);
            f32x4 my0 = *(const f32x4*)(ws + MY_OFF + k * 4);
            f32x4 my1 = *(const f32x4*)(ws + MY_OFF + k * 4 + 16);
            f32x2 mxp[4] = { {mx0[0],mx0[1]}, {mx0[2],mx0[3]}, {mx1[0],mx1[1]}, {mx1[2],mx1[3]} };
            f32x2 myp[4] = { {my0[0],my0[1]}, {my0[2],my0[3]}, {my1[0],my1[1]}, {my1[2],my1[3]} };
            f32x2 hhp[4];
            hhp[0][0] = bfbits2f(hh8.x << 16); hhp[0][1] = bfbits2f(hh8.x & 0xffff0000u);
            hhp[1][0] = bfbits2f(hh8.y << 16); hhp[1][1] = bfbits2f(hh8.y & 0xffff0000u);
            hhp[2][0] = bfbits2f(hh8.z << 16); hhp[2][1] = bfbits2f(hh8.z & 0xffff0000u);
            hhp[3][0] = bfbits2f(hh8.w << 16); hhp[3][1] = bfbits2f(hh8.w & 0xffff0000u);
            #pragma unroll
            for (int ii = 0; ii < 4; ++ii) {
                f32x2 rx2 = { rx[ii], rx[ii] };
                f32x2 ry2 = { ry[ii], ry[ii] };
                uint4 o;
                unsigned uu[4];
                #pragma unroll
                for (int p = 0; p < 4; ++p) {
                    f32x2 tt = __builtin_elementwise_fma(ry2, myp[p], hhp[p]);
                    tt = __builtin_elementwise_fma(rx2, mxp[p], tt);
                    tt = __builtin_elementwise_max(tt, zero2);
                    uu[p] = pk_bf16(tt[0], tt[1]);
                }
                o.x = uu[0]; o.y = uu[1]; o.z = uu[2]; o.w = uu[3];
                int r = (i2 * 4 + ii) * 16 + j;
                *(uint4*)(smem + Y1_LDS + y1off(r, c16)) = o;
            }
        }
    }
    __syncthreads();

    // ---- Phase C: 32x32x16 GEMM, v14 schedule + per-step phase barrier ----
    {
        const int lane31 = l & 31;           // A-frag m, C col
        const int hi = l >> 5;               // k-half; C row group
        const int sr = lane31 & 7;
        const float* A2 = (const float*)(ws + A2_OFF);
        const float* C2 = (const float*)(ws + C2_OFF);

        // addr(rt,kstep) = (av[rt] + (kstep>>2)*128) ^ ((kstep&3)<<5)
        int av[4];
        #pragma unroll
        for (int rt = 0; rt < 4; ++rt)
            av[rt] = Y1_LDS + (rt * 32 + lane31) * 1024 + ((hi ^ sr) << 4);

        const f32x16 fz16 = {0.f,0.f,0.f,0.f,0.f,0.f,0.f,0.f,
                             0.f,0.f,0.f,0.f,0.f,0.f,0.f,0.f};

        const int ctb0 = w * 4;              // chunk0 coltiles ctb0, ctb0+1
        const unsigned char* bp = ws + BP2_OFF + (ctb0 << 10) + (l << 4);
        // B addr(chunk, kstep, c) = bp + chunk*2048 + kstep*32768 + c*1024

        f32x16 acc[4][2];
        bf16x8 a0[4], a1[4];   // A double-buffer (dist-1)
        bf16x8 br[4][2];       // B ring-of-4, slot = vkstep & 3 (dist-3)
        float a2v[2], c2v[2];

        auto ldA = [&](bf16x8* dst, int add, int xorv) {
            #pragma unroll
            for (int rt = 0; rt < 4; ++rt)
                dst[rt] = *(const bf16x8*)(smem + ((av[rt] + add) ^ xorv));
        };
        auto ldB = [&](bf16x8* slot, const unsigned char* p) {
            slot[0] = *(const bf16x8*)(p);
            slot[1] = *(const bf16x8*)(p + 1024);
        };
        // m201/T5 phase: barrier-aligned MFMA cluster with priority boost.
        // Y1 LDS is read-only here -> barrier is purely a scheduling fence.
        auto mfma8 = [&](const bf16x8* a, const bf16x8* b) {
            __builtin_amdgcn_s_barrier();
            __builtin_amdgcn_s_setprio(1);
            #pragma unroll
            for (int c = 0; c < 2; ++c)
                #pragma unroll
                for (int rt = 0; rt < 4; ++rt)
                    acc[rt][c] = __builtin_amdgcn_mfma_f32_32x32x16_bf16(
                        a[rt], b[c], acc[rt][c], 0, 0, 0);
            __builtin_amdgcn_s_setprio(0);
        };
        // epilogue: bn2 + relu, maxpool over j, store fp32. 8 stores.
        // C/D 32x32: col = lane&31, row = (reg&3)+8*(reg>>2)+4*hi.
        auto epilogue = [&](int chunk) {
            #pragma unroll
            for (int c = 0; c < 2; ++c) {
                const int col = (ctb0 + chunk * 2 + c) * 32 + lane31;
                const float a2 = a2v[c], c2 = c2v[c];
                #pragma unroll
                for (int rt = 0; rt < 4; ++rt) {
                    float mv[2];
                    #pragma unroll
                    for (int hg = 0; hg < 2; ++hg) {
                        float v0 = fmaxf(fmaf(acc[rt][c][hg * 8 + 0], a2, c2), 0.f);
                        float v1 = fmaxf(fmaf(acc[rt][c][hg * 8 + 1], a2, c2), 0.f);
                        float v2 = fmaxf(fmaf(acc[rt][c][hg * 8 + 2], a2, c2), 0.f);
                        float v3 = fmaxf(fmaf(acc[rt][c][hg * 8 + 3], a2, c2), 0.f);
                        float v4 = fmaxf(fmaf(acc[rt][c][hg * 8 + 4], a2, c2), 0.f);
                        float v5 = fmaxf(fmaf(acc[rt][c][hg * 8 + 5], a2, c2), 0.f);
                        float v6 = fmaxf(fmaf(acc[rt][c][hg * 8 + 6], a2, c2), 0.f);
                        float v7 = fmaxf(fmaf(acc[rt][c][hg * 8 + 7], a2, c2), 0.f);
                        float m = fmaxf(fmaxf(fmaxf(v0, v1), fmaxf(v2, v3)),
                                        fmaxf(fmaxf(v4, v5), fmaxf(v6, v7)));
                        mv[hg] = fmaxf(m, __shfl_xor(m, 32, 64));
                    }
                    const int iloc = rt * 2 + hi;
                    const float vout = hi ? mv[1] : mv[0];
                    const int orow = s * 16 + ih * 8 + iloc;
                    __builtin_nontemporal_store(vout, &out[orow * 1024 + col]);
                }
            }
        };

        // prologue (chunk0): a2c2 (4 loads), B k0,1,2 (6 loads), A k0 (4 ds)
        a2v[0] = A2[ctb0 * 32 + lane31];        a2v[1] = A2[(ctb0 + 1) * 32 + lane31];
        c2v[0] = C2[ctb0 * 32 + lane31];        c2v[1] = C2[(ctb0 + 1) * 32 + lane31];
        #pragma unroll
        for (int rt = 0; rt < 4; ++rt) { acc[rt][0] = fz16; acc[rt][1] = fz16; }
        ldB(br[0], bp);
        ldB(br[1], bp + 32768);
        ldB(br[2], bp + 65536);
        ldA(a0, 0, 0);

        // chunk0 kq 0..6 (vk 0..27)
        #pragma unroll 1
        for (int kq = 0; kq < 7; ++kq) {
            const unsigned char* bq = bp + kq * 131072;
            const int ka = kq * 128;
            ldB(br[3], bq + 98304);  ldA(a1, ka, 32);
            WAITCNT("vmcnt(6) lgkmcnt(4)");  mfma8(a0, br[0]);
            ldB(br[0], bq + 131072); ldA(a0, ka, 64);
            WAITCNT("vmcnt(6) lgkmcnt(4)");  mfma8(a1, br[1]);
            ldB(br[1], bq + 163840); ldA(a1, ka, 96);
            WAITCNT("vmcnt(6) lgkmcnt(4)");  mfma8(a0, br[2]);
            ldB(br[2], bq + 196608); ldA(a0, ka + 128, 0);
            WAITCNT("vmcnt(6) lgkmcnt(4)");  mfma8(a1, br[3]);
        }
        // kq7 (vk 28..31): B prefetch rolls into chunk1 ksteps 0..2
        {
            const unsigned char* bq = bp + 7 * 131072;
            const unsigned char* b1 = bp + 2048;
            const int ka = 7 * 128;
            ldB(br[3], bq + 98304);  ldA(a1, ka, 32);
            WAITCNT("vmcnt(6) lgkmcnt(4)");  mfma8(a0, br[0]);
            ldB(br[0], b1);          ldA(a0, ka, 64);
            WAITCNT("vmcnt(6) lgkmcnt(4)");  mfma8(a1, br[1]);
            ldB(br[1], b1 + 32768);  ldA(a1, ka, 96);
            WAITCNT("vmcnt(6) lgkmcnt(4)");  mfma8(a0, br[2]);
            ldB(br[2], b1 + 65536);  ldA(a0, 0, 0);   // A for chunk1 k0
            WAITCNT("vmcnt(6) lgkmcnt(4)");  mfma8(a1, br[3]);
        }
        // boundary: epilogue chunk0 (8 stores), a2c2 chunk1 (4 loads), reset acc
        __builtin_amdgcn_sched_barrier(0);
        epilogue(0);
        a2v[0] = A2[(ctb0 + 2) * 32 + lane31];  a2v[1] = A2[(ctb0 + 3) * 32 + lane31];
        c2v[0] = C2[(ctb0 + 2) * 32 + lane31];  c2v[1] = C2[(ctb0 + 3) * 32 + lane31];
        #pragma unroll
        for (int rt = 0; rt < 4; ++rt) { acc[rt][0] = fz16; acc[rt][1] = fz16; }
        __builtin_amdgcn_sched_barrier(0);
        // chunk1 kq8 (vk 32..35): first 3 waits count 8 stores + 4 loads
        {
            const unsigned char* bq = bp + 2048;
            ldB(br[3], bq + 98304);  ldA(a1, 0, 32);
            WAITCNT("vmcnt(18) lgkmcnt(4)"); mfma8(a0, br[0]);
            ldB(br[0], bq + 131072); ldA(a0, 0, 64);
            WAITCNT("vmcnt(18) lgkmcnt(4)"); mfma8(a1, br[1]);
            ldB(br[1], bq + 163840); ldA(a1, 0, 96);
            WAITCNT("vmcnt(18) lgkmcnt(4)"); mfma8(a0, br[2]);
            ldB(br[2], bq + 196608); ldA(a0, 128, 0);
            WAITCNT("vmcnt(6) lgkmcnt(4)");  mfma8(a1, br[3]);
        }
        // chunk1 kq 9..14 (vk 36..59)
        #pragma unroll 1
        for (int kq = 1; kq < 7; ++kq) {
            const unsigned char* bq = bp + 2048 + kq * 131072;
            const int ka = kq * 128;
            ldB(br[3], bq + 98304);  ldA(a1, ka, 32);
            WAITCNT("vmcnt(6) lgkmcnt(4)");  mfma8(a0, br[0]);
            ldB(br[0], bq + 131072); ldA(a0, ka, 64);
            WAITCNT("vmcnt(6) lgkmcnt(4)");  mfma8(a1, br[1]);
            ldB(br[1], bq + 163840); ldA(a1, ka, 96);
            WAITCNT("vmcnt(6) lgkmcnt(4)");  mfma8(a0, br[2]);
            ldB(br[2], bq + 196608); ldA(a0, ka + 128, 0);
            WAITCNT("vmcnt(6) lgkmcnt(4)");  mfma8(a1, br[3]);
        }
        // kq15 tail (vk 60..63)
        {
            const unsigned char* bq = bp + 2048 + 7 * 131072;
            const int ka = 7 * 128;
            ldB(br[3], bq + 98304);  ldA(a1, ka, 32);
            WAITCNT("vmcnt(6) lgkmcnt(4)");  mfma8(a0, br[0]);
            ldA(a0, ka, 64);
            WAITCNT("vmcnt(4) lgkmcnt(4)");  mfma8(a1, br[1]);
            ldA(a1, ka, 96);
            WAITCNT("vmcnt(2) lgkmcnt(4)");  mfma8(a0, br[2]);
            WAITCNT("vmcnt(0) lgkmcnt(0)");  mfma8(a1, br[3]);
        }
        __builtin_amdgcn_sched_barrier(0);
        epilogue(1);
    }
}

extern "C" void kernel_launch(void* const* d_in, const int* in_sizes, int n_in,
                              void* d_out, int out_size, void* d_ws, size_t ws_size,
                              hipStream_t stream) {
    const float* hst  = (const float*)d_in[0];
    const float* epos = (const float*)d_in[1];
    const float* Wsp  = (const float*)d_in[4];
    const float* bsp  = (const float*)d_in[5];
    const float* Wp1  = (const float*)d_in[20];
    const float* bp1  = (const float*)d_in[21];
    const float* gp1  = (const float*)d_in[22];
    const float* btp1 = (const float*)d_in[23];
    const float* mp1  = (const float*)d_in[24];
    const float* vp1  = (const float*)d_in[25];
    const float* Wp2  = (const float*)d_in[26];
    const float* bp2  = (const float*)d_in[27];
    const float* gp2  = (const float*)d_in[28];
    const float* btp2 = (const float*)d_in[29];
    const float* mp2  = (const float*)d_in[30];
    const float* vp2  = (const float*)d_in[31];
    unsigned char* ws = (unsigned char*)d_ws;
    float* out = (float*)d_out;

    // 256 (Wp2 pack) + 16 (W1b pack) + 8 (k-consts) + 4 (A2/C2) = 284 blocks
    prep_pack_kernel<<<284, 256, 0, stream>>>(Wsp, bsp, Wp1, bp1, gp1, btp1, mp1, vp1,
                                              Wp2, bp2, gp2, btp2, mp2, vp2, ws);
    // 256 scenes x 2 i-halves, 512 threads (8 waves)
    mm2_kernel<<<512, 512, 0, stream>>>(hst, epos, ws, out);
}